// Round 7
// baseline (13416.142 us; speedup 1.0000x reference)
//
#include <hip/hip_runtime.h>
#include <math.h>

#define TT 2048
#define BB 64
#define II 64
#define HH 512
#define OO 32
#define OCC 8

// 8 k-groups x 64 rows. Per group: rows 0..19 VGPR (80 floats/thread),
// rows 20..27 LDS (64 rows total = 128 KB), rows 28..63 streamed (576 KB/step).
#define VR 20
#define LR 8
#define SR 36

// d_out layout: output [T,B,32] | output_ctx [T,B,8] | rate_all [T,B,512]
#define OUT1_OFF ((size_t)TT * BB * OO)
#define RATE_OFF (OUT1_OFF + (size_t)TT * BB * OCC)

// dynamic LDS: wlds[64][512] | st[2][512] | parts[8][512]  = 148 KB
#define LDS_W_FLOATS (64 * HH)
#define LDS_FLOATS (LDS_W_FLOATS + 2 * HH + 8 * HH)

// ---------------------------------------------------------------------------
// Pack Wcat[k][h] = Wh[h][k]  (k-major, coalesced in h).
// ---------------------------------------------------------------------------
__global__ __launch_bounds__(256) void pack_weights(
    const float* __restrict__ Wh, float* __restrict__ Wcat)
{
    int idx = blockIdx.x * 256 + threadIdx.x;
    int k = idx >> 9;
    int h = idx & (HH - 1);
    Wcat[idx] = Wh[h * HH + k];
}

// ---------------------------------------------------------------------------
// Prefold: pre[t,b,h] = x[t,b,:] @ Wi[h,:] + bi[h] + bh[h] + NS*noise[t,b,h]
// written INTO the rate region of d_out (scan reads row then overwrites it).
// ---------------------------------------------------------------------------
__global__ __launch_bounds__(512) void prefold(
    const float* __restrict__ x, const float* __restrict__ noise,
    const float* __restrict__ Wi, const float* __restrict__ bi,
    const float* __restrict__ bh, float* __restrict__ pre)
{
    __shared__ float xs[8][II];
    const int tid = threadIdx.x;
    const size_t row0 = (size_t)blockIdx.x * 8;

    const double SIG = 1.5 / sqrt(512.0);
    const float  NS  = (float)sqrt(2.0 * SIG * SIG / 0.1);

    float wi[II];
    #pragma unroll
    for (int k4 = 0; k4 < II / 4; ++k4)
        *(float4*)&wi[4 * k4] = *(const float4*)&Wi[(size_t)tid * II + 4 * k4];
    const float bsum = bi[tid] + bh[tid];

    xs[tid >> 6][tid & 63] = x[(row0 + (tid >> 6)) * II + (tid & 63)];
    __syncthreads();

    #pragma unroll 2
    for (int r = 0; r < 8; ++r) {
        float acc = bsum + NS * noise[(row0 + r) * HH + tid];
        #pragma unroll
        for (int k4 = 0; k4 < II / 4; ++k4) {
            float4 xv = *(const float4*)&xs[r][4 * k4];
            acc += wi[4*k4] * xv.x + wi[4*k4+1] * xv.y
                 + wi[4*k4+2] * xv.z + wi[4*k4+3] * xv.w;
        }
        pre[(row0 + r) * HH + tid] = acc;
    }
}

// ---------------------------------------------------------------------------
// Recurrent scan: one 1024-thread WG per batch (16 waves = 4/SIMD for
// VMEM latency hiding -- round-3-proven; round-6's 2/SIMD ran at 66% L1 BW).
// Thread (g = tid>>7, ht = tid&127): group g owns k-rows [64g,64g+64),
// thread owns h-cols 4ht..4ht+3; threads tid<512 own h=tid for the update.
// ---------------------------------------------------------------------------
__global__ __launch_bounds__(1024) void rnn_scan7(
    const float* __restrict__ rate0,   // [B,H]
    const float* __restrict__ Wcat,    // [512][512] = Wh^T
    float* __restrict__ pre_rate)      // [T,B,H]: in = pre, out = rate
{
    extern __shared__ float lds[];
    float* wlds  = lds;                     // [64][512]
    float* stbuf = lds + LDS_W_FLOATS;      // [2][512]
    float* parts = stbuf + 2 * HH;          // [8][512]

    const int b   = blockIdx.x;
    const int tid = threadIdx.x;
    const int g   = tid >> 7;               // k-group 0..7
    const int ht  = tid & 127;
    const int h4  = 4 * ht;
    const int kb  = g * 64;                 // group k-base

    // ---- VGPR-resident weights: rows kb+0..19, cols h4..h4+3
    float4 wreg[VR];
    #pragma unroll
    for (int m = 0; m < VR; ++m)
        wreg[m] = *(const float4*)&Wcat[(size_t)(kb + m) * HH + h4];

    // ---- LDS-resident weights: local row rl <-> k = (rl>>3)*64 + 20 + (rl&7)
    for (int idx = tid; idx < 64 * 128; idx += 1024) {
        int rl = idx >> 7;
        int c4 = (idx & 127) * 4;
        int k  = (rl >> 3) * 64 + 20 + (rl & 7);
        *(float4*)&wlds[rl * HH + c4] = *(const float4*)&Wcat[(size_t)k * HH + c4];
    }

    float rf = 0.f;
    if (tid < HH) {
        rf = rate0[b * HH + tid];
        stbuf[tid] = rf;                    // st[0]
    }
    __syncthreads();

    const float* wstream = Wcat + (size_t)(kb + VR + LR) * HH + h4;

    for (int t = 0; t < TT; ++t) {
        const int cur = t & 1, nxt = cur ^ 1;
        const size_t row = ((size_t)t * BB + b) * HH;
        const float* stc = stbuf + cur * HH;

        float pre_val = 0.f;
        if (tid < HH) pre_val = pre_rate[row + tid];   // hides under dot

        float a0 = 0.f, a1 = 0.f, a2 = 0.f, a3 = 0.f;

        // ---- streamed rows 28..63 (2 rows/iter, unroll 2: ~20 regs in flight)
        {
            const float* wp = wstream;
            #pragma unroll 2
            for (int sm = 0; sm < SR / 2; ++sm) {
                float2 s2 = *(const float2*)&stc[kb + VR + LR + 2 * sm];
                float4 w0 = *(const float4*)(wp);
                float4 w1 = *(const float4*)(wp + HH);
                a0 += w0.x*s2.x + w1.x*s2.y;
                a1 += w0.y*s2.x + w1.y*s2.y;
                a2 += w0.z*s2.x + w1.z*s2.y;
                a3 += w0.w*s2.x + w1.w*s2.y;
                wp += 2 * HH;
            }
        }

        // ---- VGPR rows 0..19
        #pragma unroll
        for (int m = 0; m < VR / 4; ++m) {
            float4 s4 = *(const float4*)&stc[kb + 4 * m];
            a0 += wreg[4*m].x*s4.x + wreg[4*m+1].x*s4.y + wreg[4*m+2].x*s4.z + wreg[4*m+3].x*s4.w;
            a1 += wreg[4*m].y*s4.x + wreg[4*m+1].y*s4.y + wreg[4*m+2].y*s4.z + wreg[4*m+3].y*s4.w;
            a2 += wreg[4*m].z*s4.x + wreg[4*m+1].z*s4.y + wreg[4*m+2].z*s4.z + wreg[4*m+3].z*s4.w;
            a3 += wreg[4*m].w*s4.x + wreg[4*m+1].w*s4.y + wreg[4*m+2].w*s4.z + wreg[4*m+3].w*s4.w;
        }

        // ---- LDS rows 20..27 (local rows g*8 + 0..7)
        #pragma unroll
        for (int lm = 0; lm < LR / 4; ++lm) {
            float4 s4 = *(const float4*)&stc[kb + VR + 4 * lm];
            const float* wl = &wlds[(g * 8 + 4 * lm) * HH + h4];
            float4 w0 = *(const float4*)(wl);
            float4 w1 = *(const float4*)(wl + HH);
            float4 w2 = *(const float4*)(wl + 2 * HH);
            float4 w3 = *(const float4*)(wl + 3 * HH);
            a0 += w0.x*s4.x + w1.x*s4.y + w2.x*s4.z + w3.x*s4.w;
            a1 += w0.y*s4.x + w1.y*s4.y + w2.y*s4.z + w3.y*s4.w;
            a2 += w0.z*s4.x + w1.z*s4.y + w2.z*s4.z + w3.z*s4.w;
            a3 += w0.w*s4.x + w1.w*s4.y + w2.w*s4.z + w3.w*s4.w;
        }

        *(float4*)&parts[g * HH + h4] = make_float4(a0, a1, a2, a3);
        __syncthreads();                    // parts complete; st[cur] reads done

        // ---- reduce + update: thread tid (<512) owns h = tid
        if (tid < HH) {
            float sum = 0.f;
            #pragma unroll
            for (int p = 0; p < 8; ++p) sum += parts[p * HH + tid];
            float pre = sum + pre_val;
            rf = 0.9f * rf + 0.1f * tanhf(pre);
            pre_rate[row + tid] = rf;       // overwrite pre with rate
            stbuf[nxt * HH + tid] = rf;
        }
        __syncthreads();                    // st[nxt] ready; parts reads done
    }
}

// ---------------------------------------------------------------------------
// Readouts: 8 rows per 256-thread block, rows staged in LDS, float4 dots.
// ---------------------------------------------------------------------------
__global__ __launch_bounds__(256) void readout(
    const float* __restrict__ rate_all,
    const float* __restrict__ Wo,  const float* __restrict__ bo,
    const float* __restrict__ Woc, const float* __restrict__ boc,
    float* __restrict__ out, float* __restrict__ outc)
{
    __shared__ float rbuf[8][HH];
    const int tid  = threadIdx.x;
    const size_t row0 = (size_t)blockIdx.x * 8;

    for (int i = tid; i < 8 * (HH / 4); i += 256) {
        int r = i >> 7, c = (i & 127) * 4;
        *(float4*)&rbuf[r][c] = *(const float4*)&rate_all[(row0 + r) * HH + c];
    }
    __syncthreads();

    {
        int r = tid >> 5, o = tid & 31;
        const float* w = Wo + (size_t)o * HH;
        float acc = 0.f;
        #pragma unroll 4
        for (int h = 0; h < HH; h += 4) {
            float4 rv = *(const float4*)&rbuf[r][h];
            float4 wv = *(const float4*)&w[h];
            acc += rv.x * wv.x + rv.y * wv.y + rv.z * wv.z + rv.w * wv.w;
        }
        out[(row0 + r) * OO + o] = acc + bo[o];
    }
    if (tid < 64) {
        int r = tid >> 3, oc = tid & 7;
        const float* w = Woc + (size_t)oc * HH;
        float acc = 0.f;
        #pragma unroll 4
        for (int h = 0; h < HH; h += 4) {
            float4 rv = *(const float4*)&rbuf[r][h];
            float4 wv = *(const float4*)&w[h];
            acc += rv.x * wv.x + rv.y * wv.y + rv.z * wv.z + rv.w * wv.w;
        }
        outc[(row0 + r) * OCC + oc] = acc + boc[oc];
    }
}

// ---------------------------------------------------------------------------
extern "C" void kernel_launch(void* const* d_in, const int* in_sizes, int n_in,
                              void* d_out, int out_size, void* d_ws, size_t ws_size,
                              hipStream_t stream)
{
    const float* x     = (const float*)d_in[0];
    const float* rate0 = (const float*)d_in[1];
    const float* noise = (const float*)d_in[2];
    const float* Wi    = (const float*)d_in[3];
    const float* bi    = (const float*)d_in[4];
    const float* Wh    = (const float*)d_in[5];
    const float* bh    = (const float*)d_in[6];
    const float* Wo    = (const float*)d_in[7];
    const float* bo    = (const float*)d_in[8];
    const float* Woc   = (const float*)d_in[9];
    const float* boc   = (const float*)d_in[10];

    float* out   = (float*)d_out;
    float* rateb = out + RATE_OFF;          // pre, then rate
    float* Wcat  = (float*)d_ws;            // 512*512 fp32 = 1 MB

    // idempotent, value-deterministic host-side attribute (not a stream op)
    hipFuncSetAttribute((const void*)rnn_scan7,
                        hipFuncAttributeMaxDynamicSharedMemorySize,
                        LDS_FLOATS * sizeof(float));

    pack_weights<<<HH * HH / 256, 256, 0, stream>>>(Wh, Wcat);
    prefold<<<TT * BB / 8, 512, 0, stream>>>(x, noise, Wi, bi, bh, rateb);
    rnn_scan7<<<BB, 1024, LDS_FLOATS * sizeof(float), stream>>>(rate0, Wcat, rateb);
    readout<<<TT * BB / 8, 256, 0, stream>>>(rateb, Wo, bo, Woc, boc,
                                             out, out + OUT1_OFF);
}

// Round 9
// 5775.850 us; speedup vs baseline: 2.3228x; 2.3228x over previous
//
#include <hip/hip_runtime.h>
#include <math.h>

#define TT 2048
#define BB 64
#define II 64
#define HH 512
#define OO 32
#define OCC 8
#define QS 128   // k/h slice per WG (4-way split)

// d_out layout: output [T,B,32] | output_ctx [T,B,8] | rate_all [T,B,512]
#define OUT1_OFF ((size_t)TT * BB * OO)
#define RATE_OFF (OUT1_OFF + (size_t)TT * BB * OCC)

// d_ws layout: P[B][4][2][HH] floats (1 MB) | flags int[B*4*16] @ 1 MB
#define FLAG_BYTE_OFF ((size_t)1 << 20)
#define FLAG_BYTES (BB * 4 * 16 * sizeof(int))

// ---------------------------------------------------------------------------
// Prefold: pre[t,b,h] = x[t,b,:] @ Wi[h,:] + bi[h] + bh[h] + NS*noise[t,b,h]
// written INTO the rate region of d_out (scan reads row then overwrites it).
// ---------------------------------------------------------------------------
__global__ __launch_bounds__(512) void prefold(
    const float* __restrict__ x, const float* __restrict__ noise,
    const float* __restrict__ Wi, const float* __restrict__ bi,
    const float* __restrict__ bh, float* __restrict__ pre)
{
    __shared__ float xs[8][II];
    const int tid = threadIdx.x;
    const size_t row0 = (size_t)blockIdx.x * 8;

    const double SIG = 1.5 / sqrt(512.0);
    const float  NS  = (float)sqrt(2.0 * SIG * SIG / 0.1);

    float wi[II];
    #pragma unroll
    for (int k4 = 0; k4 < II / 4; ++k4)
        *(float4*)&wi[4 * k4] = *(const float4*)&Wi[(size_t)tid * II + 4 * k4];
    const float bsum = bi[tid] + bh[tid];

    xs[tid >> 6][tid & 63] = x[(row0 + (tid >> 6)) * II + (tid & 63)];
    __syncthreads();

    #pragma unroll 2
    for (int r = 0; r < 8; ++r) {
        float acc = bsum + NS * noise[(row0 + r) * HH + tid];
        #pragma unroll
        for (int k4 = 0; k4 < II / 4; ++k4) {
            float4 xv = *(const float4*)&xs[r][4 * k4];
            acc += wi[4*k4] * xv.x + wi[4*k4+1] * xv.y
                 + wi[4*k4+2] * xv.z + wi[4*k4+3] * xv.w;
        }
        pre[(row0 + r) * HH + tid] = acc;
    }
}

// ---------------------------------------------------------------------------
// Recurrent scan, 4-way k-split, weights fully VGPR-resident, cross-WG sync
// via agent-scope RELAXED atomics only (IF-direct; no release/acquire cache
// maintenance -- round 4's storm). WG (q,b) at bid=q*64+b owns k-slice AND
// h-slice [128q,128q+128). 1024 threads: g=tid>>7 -> 16 k-rows, ht=tid&127
// -> h-cols 4ht..4ht+3.
// SYNC LESSON (round 8 hang): flag store and peer polls MUST be in different
// waves. A divergent same-wave if{store}else{poll} can schedule the poll side
// first and the store never issues -> cross-WG circular wait -> deadlock.
// Here: tid==0 (wave 0) stores; tid==64/128/192 (waves 1-3) poll one peer each.
// Ordering: __syncthreads (B2) emits s_waitcnt vmcnt(0) per wave, so all P
// stores are IF-acked before the flag store issues (in-order wave issue).
// Parity-double-buffered P; race-freedom by the round-4 flag-chain argument.
// ---------------------------------------------------------------------------
__global__ __launch_bounds__(1024) void rnn_scan9(
    const float* __restrict__ rate0,   // [B,H]
    const float* __restrict__ Wh,      // [H,H] row-major
    float* __restrict__ pre_rate,      // [T,B,H]: in = pre, out = rate
    float* P,                          // [B][4][2][HH] (IF-direct)
    int* flags)                        // [B*4*16]
{
    __shared__ float st[QS];           // own state slice
    __shared__ float parts[8 * HH];    // per-g partials for ALL 512 h (16 KB)
    __shared__ float red[HH];          // reduced sums (for own-slice consume)

    const int bid = blockIdx.x;
    const int q   = bid >> 6;          // quarter 0..3
    const int b   = bid & 63;          // batch
    const int tid = threadIdx.x;
    const int g   = tid >> 7;          // 0..7 -> 16 k-rows each
    const int ht  = tid & 127;
    const int h4  = 4 * ht;
    const int kq  = q * QS + g * 16;

    // Weights fully resident: wreg[m] = W^T[kq+m][h4..h4+3] = Wh[h4+c][kq+m].
    float4 wreg[16];
    #pragma unroll
    for (int m = 0; m < 16; ++m) {
        wreg[m].x = Wh[(size_t)(h4 + 0) * HH + kq + m];
        wreg[m].y = Wh[(size_t)(h4 + 1) * HH + kq + m];
        wreg[m].z = Wh[(size_t)(h4 + 2) * HH + kq + m];
        wreg[m].w = Wh[(size_t)(h4 + 3) * HH + kq + m];
    }

    float rf = 0.f;
    if (tid < QS) {
        rf = rate0[b * HH + q * QS + tid];
        st[tid] = rf;
    }
    int* myflag = &flags[(b * 4 + q) * 16];
    __syncthreads();

    for (int t = 0; t < TT; ++t) {
        const int par = t & 1;
        const size_t row = ((size_t)t * BB + b) * HH;

        float pre_val = 0.f;
        if (tid < QS) pre_val = pre_rate[row + q * QS + tid];  // hides under dot

        // ---- dot: this thread's 4 h-cols over its 16 k-rows (st broadcast)
        float a0 = 0.f, a1 = 0.f, a2 = 0.f, a3 = 0.f;
        #pragma unroll
        for (int mm = 0; mm < 4; ++mm) {
            float4 s4 = *(const float4*)&st[g * 16 + 4 * mm];
            a0 += wreg[4*mm].x*s4.x + wreg[4*mm+1].x*s4.y + wreg[4*mm+2].x*s4.z + wreg[4*mm+3].x*s4.w;
            a1 += wreg[4*mm].y*s4.x + wreg[4*mm+1].y*s4.y + wreg[4*mm+2].y*s4.z + wreg[4*mm+3].y*s4.w;
            a2 += wreg[4*mm].z*s4.x + wreg[4*mm+1].z*s4.y + wreg[4*mm+2].z*s4.z + wreg[4*mm+3].z*s4.w;
            a3 += wreg[4*mm].w*s4.x + wreg[4*mm+1].w*s4.y + wreg[4*mm+2].w*s4.z + wreg[4*mm+3].w*s4.w;
        }
        *(float4*)&parts[g * HH + h4] = make_float4(a0, a1, a2, a3);
        __syncthreads();                      // B1: parts ready

        // ---- reduce over g; publish full 512-wide partial to IF; keep in LDS
        if (tid < HH) {
            float s = 0.f;
            #pragma unroll
            for (int p = 0; p < 8; ++p) s += parts[p * HH + tid];
            red[tid] = s;
            __hip_atomic_store(&P[(((size_t)b * 4 + q) * 2 + par) * HH + tid], s,
                               __ATOMIC_RELAXED, __HIP_MEMORY_SCOPE_AGENT);
        }
        __syncthreads();                      // B2: all waves vmcnt(0) -> P at IF

        // ---- flag publish (wave 0) / peer polls (waves 1..3) -- see header
        if (tid == 0) {
            __hip_atomic_store(myflag, t + 1, __ATOMIC_RELAXED,
                               __HIP_MEMORY_SCOPE_AGENT);
        } else if (tid == 64 || tid == 128 || tid == 192) {
            int* f = &flags[(b * 4 + ((q + (tid >> 6)) & 3)) * 16];
            while (__hip_atomic_load(f, __ATOMIC_RELAXED,
                                     __HIP_MEMORY_SCOPE_AGENT) < t + 1) {}
        }
        __syncthreads();                      // B3: peers' P published

        // ---- consume: own-slice update (h = q*128 + tid, tid < 128)
        if (tid < QS) {
            const int h = q * QS + tid;
            float tot = pre_val + red[h];
            #pragma unroll
            for (int j = 1; j < 4; ++j) {
                const int pj = (q + j) & 3;
                tot += __hip_atomic_load(
                    &P[(((size_t)b * 4 + pj) * 2 + par) * HH + h],
                    __ATOMIC_RELAXED, __HIP_MEMORY_SCOPE_AGENT);
            }
            rf = 0.9f * rf + 0.1f * tanhf(tot);
            pre_rate[row + h] = rf;           // overwrite pre with rate
            st[tid] = rf;
        }
        __syncthreads();                      // B4: st ready for next dot
    }
}

// ---------------------------------------------------------------------------
// Readouts: 8 rows per 256-thread block, rows staged in LDS, float4 dots.
// ---------------------------------------------------------------------------
__global__ __launch_bounds__(256) void readout(
    const float* __restrict__ rate_all,
    const float* __restrict__ Wo,  const float* __restrict__ bo,
    const float* __restrict__ Woc, const float* __restrict__ boc,
    float* __restrict__ out, float* __restrict__ outc)
{
    __shared__ float rbuf[8][HH];
    const int tid  = threadIdx.x;
    const size_t row0 = (size_t)blockIdx.x * 8;

    for (int i = tid; i < 8 * (HH / 4); i += 256) {
        int r = i >> 7, c = (i & 127) * 4;
        *(float4*)&rbuf[r][c] = *(const float4*)&rate_all[(row0 + r) * HH + c];
    }
    __syncthreads();

    {
        int r = tid >> 5, o = tid & 31;
        const float* w = Wo + (size_t)o * HH;
        float acc = 0.f;
        #pragma unroll 4
        for (int h = 0; h < HH; h += 4) {
            float4 rv = *(const float4*)&rbuf[r][h];
            float4 wv = *(const float4*)&w[h];
            acc += rv.x * wv.x + rv.y * wv.y + rv.z * wv.z + rv.w * wv.w;
        }
        out[(row0 + r) * OO + o] = acc + bo[o];
    }
    if (tid < 64) {
        int r = tid >> 3, oc = tid & 7;
        const float* w = Woc + (size_t)oc * HH;
        float acc = 0.f;
        #pragma unroll 4
        for (int h = 0; h < HH; h += 4) {
            float4 rv = *(const float4*)&rbuf[r][h];
            float4 wv = *(const float4*)&w[h];
            acc += rv.x * wv.x + rv.y * wv.y + rv.z * wv.z + rv.w * wv.w;
        }
        outc[(row0 + r) * OCC + oc] = acc + boc[oc];
    }
}

// ---------------------------------------------------------------------------
extern "C" void kernel_launch(void* const* d_in, const int* in_sizes, int n_in,
                              void* d_out, int out_size, void* d_ws, size_t ws_size,
                              hipStream_t stream)
{
    const float* x     = (const float*)d_in[0];
    const float* rate0 = (const float*)d_in[1];
    const float* noise = (const float*)d_in[2];
    const float* Wi    = (const float*)d_in[3];
    const float* bi    = (const float*)d_in[4];
    const float* Wh    = (const float*)d_in[5];
    const float* bh    = (const float*)d_in[6];
    const float* Wo    = (const float*)d_in[7];
    const float* bo    = (const float*)d_in[8];
    const float* Woc   = (const float*)d_in[9];
    const float* boc   = (const float*)d_in[10];

    float* out   = (float*)d_out;
    float* rateb = out + RATE_OFF;          // pre, then rate
    float* P     = (float*)d_ws;
    int*   flags = (int*)((char*)d_ws + FLAG_BYTE_OFF);

    hipMemsetAsync(flags, 0, FLAG_BYTES, stream);   // ws is not re-poisoned
    prefold<<<TT * BB / 8, 512, 0, stream>>>(x, noise, Wi, bi, bh, rateb);
    rnn_scan9<<<4 * BB, 1024, 0, stream>>>(rate0, Wh, rateb, P, flags);
    readout<<<TT * BB / 8, 256, 0, stream>>>(rateb, Wo, bo, Woc, boc,
                                             out, out + OUT1_OFF);
}